// Round 3
// baseline (1950.241 us; speedup 1.0000x reference)
//
#include <hip/hip_runtime.h>
#include <hip/hip_bf16.h>

#define S_LEN 2048
#define DH    128
#define NBH   32
#define KPAD  136         // Ks row pitch in halves (272B)
#define VPAD  72          // Vt row pitch in halves (144B)

typedef __attribute__((ext_vector_type(4))) float    f32x4;
typedef __attribute__((ext_vector_type(8))) _Float16 h16x8;
typedef __attribute__((ext_vector_type(4))) _Float16 h16x4;
typedef __attribute__((ext_vector_type(2))) __fp16   fp16x2;

#if __has_builtin(__builtin_amdgcn_exp2f)
#define EXP2(x) __builtin_amdgcn_exp2f(x)
#else
#define EXP2(x) exp2f(x)
#endif

static __device__ __forceinline__ unsigned pk2(float lo, float hi) {
  union { fp16x2 h; unsigned u; } u;
  u.h = __builtin_amdgcn_cvt_pkrtz(lo, hi);
  return u.u;
}

// Block = two 64-row q-strips (jq and 31-jq) of one (b,h), ONE k-sweep.
// XCD swizzle: flat%8 == bh%8 -> all 16 blocks of a (b,h) on one XCD (K/V L2-resident).
// Complementary pairing: CU slots m and m+32 get jq and 15-jq -> 49 iters per CU.
// Double-buffered LDS: ONE barrier per k-iteration.
//
// PV path: O^T += V^T * P^T via v_mfma_f32_16x16x16_f16.  The swapped-QK^T
// softmax layout (lane(quad,l16) holds P[q=l16][k=16t+4*quad+r], packed as
// fp16 pairs) IS the B-operand layout of the K=16 MFMA -> zero-shuffle PV.
// O^T accumulator => alpha and 1/l are per-lane scalars (no broadcasts), and
// lane's O slice O[q=l16][d=dt*16+quad*4 .. +3] is a contiguous f32x4 ->
// direct vector stores, no transpose epilogue.
//
// PRESSURE FIX (vs round 1/2 spill): write_tile(buf^1) moved to right after
// QK^T, so the 64 f32 staging regs (ka/va) die BEFORE the softmax/PV window
// (the QK^T section covers L2-resident K/V load latency).  V-fragment LDS
// addresses precomputed once (vq/vt16, 16 stable regs) instead of per-iter
// temporaries.
__global__ __launch_bounds__(256, 2)
void attn_fwd(const float* __restrict__ Q, const float* __restrict__ K,
              const float* __restrict__ V, const float* __restrict__ scale,
              float* __restrict__ O) {
  __shared__ __align__(16) short Ks[2][64 * KPAD];
  __shared__ __align__(16) short Vt[2][128 * VPAD];

  const int tid  = threadIdx.x;
  const int w    = tid >> 6;
  const int lane = tid & 63;
  const int quad = lane >> 4;
  const int l16  = lane & 15;

  const int flat = (int)blockIdx.x;
  const int m_   = flat >> 3;
  const int jqi  = m_ & 15;
  const int bhh  = m_ >> 4;                       // 0..3
  const int jq   = (bhh & 2) ? (15 - jqi) : jqi;  // complement on second CU slot
  const int bh   = (flat & 7) | (bhh << 3);

  const size_t base = (size_t)bh * (S_LEN * DH);
  const float sc = scale[0] * 1.44269504088896340736f;  // fold log2(e)

  const int krow = tid >> 2, kcolf = (tid & 3) * 32;    // K staging: 4 thr/row
  const int vd = (tid & 31) * 4, vkb = (tid >> 5) * 4;  // V staging: 4k x 4d transpose

  // PV A-operand (V^T) address tables, computed ONCE:
  // lane(quad,l16) needs V[k=16t+4*quad+e][d=dt*16+l16], e=0..3
  // = Vt row d, chunk (4t+quad)^mm, mm=(d^(d>>4))&14 (staging swizzle).
  // (4t+quad)^mm = 4*(t^(mm>>2)) + (quad^(mm&2))   (aligned bit fields)
  int vq[8], vt16[8];
#pragma unroll
  for (int dt = 0; dt < 8; ++dt) {
    const int row = dt * 16 + l16;
    const int mm = (row ^ (row >> 4)) & 14;
    vq[dt]   = row * VPAD + ((quad ^ (mm & 2)) << 2);
    vt16[dt] = (mm >> 2) << 4;
  }

  const int q0A = jq * 64;
  const int q0B = (31 - jq) * 64;
  const int nkt = 32 - jq;
  const int qrowA = q0A + w * 16 + l16;
  const int qrowB = q0B + w * 16 + l16;

  h16x8 qfA[4], qfB[4];
  {
    const float* qpA = Q + base + (size_t)qrowA * DH + quad * 8;
    const float* qpB = Q + base + (size_t)qrowB * DH + quad * 8;
#pragma unroll
    for (int f = 0; f < 4; ++f) {
      f32x4 a = *(const f32x4*)(qpA + f * 32);
      f32x4 b = *(const f32x4*)(qpA + f * 32 + 4);
      union { h16x8 v; unsigned u[4]; } t;
      t.u[0] = pk2(a[0] * sc, a[1] * sc);
      t.u[1] = pk2(a[2] * sc, a[3] * sc);
      t.u[2] = pk2(b[0] * sc, b[1] * sc);
      t.u[3] = pk2(b[2] * sc, b[3] * sc);
      qfA[f] = t.v;
      a = *(const f32x4*)(qpB + f * 32);
      b = *(const f32x4*)(qpB + f * 32 + 4);
      t.u[0] = pk2(a[0] * sc, a[1] * sc);
      t.u[1] = pk2(a[2] * sc, a[3] * sc);
      t.u[2] = pk2(b[0] * sc, b[1] * sc);
      t.u[3] = pk2(b[2] * sc, b[3] * sc);
      qfB[f] = t.v;
    }
  }

  // O^T accumulators: O*[dt][r] = O[q=l16][d=dt*16+4*quad+r]
  f32x4 OA[8], OB[8];
#pragma unroll
  for (int i = 0; i < 8; ++i) { OA[i] = (f32x4){0.f,0.f,0.f,0.f}; OB[i] = (f32x4){0.f,0.f,0.f,0.f}; }
  float mA = -1e30f, lA = 0.f, mB = -1e30f, lB = 0.f;

  // Unconditional online-softmax; per-lane alpha (acc q == l16); fused exp2+pack.
  auto softmax_pack = [&](f32x4* st, float& m_run, float& l_run, f32x4* Oacc, int* pd) {
    float mt = st[0][0];
#pragma unroll
    for (int t = 0; t < 4; ++t)
#pragma unroll
      for (int r = 0; r < 4; ++r) mt = fmaxf(mt, st[t][r]);
    mt = fmaxf(mt, __shfl_xor(mt, 16));
    mt = fmaxf(mt, __shfl_xor(mt, 32));
    const float m_new = fmaxf(m_run, mt);
    const float alpha = EXP2(m_run - m_new);
    m_run = m_new;
    float rs = 0.f;
#pragma unroll
    for (int t = 0; t < 4; ++t) {
      const float p0 = EXP2(st[t][0] - m_new);
      const float p1 = EXP2(st[t][1] - m_new);
      const float p2 = EXP2(st[t][2] - m_new);
      const float p3 = EXP2(st[t][3] - m_new);
      rs += (p0 + p1) + (p2 + p3);
      pd[t*2]   = (int)pk2(p0, p1);
      pd[t*2+1] = (int)pk2(p2, p3);
    }
    rs += __shfl_xor(rs, 16);
    rs += __shfl_xor(rs, 32);
    l_run = l_run * alpha + rs;
#pragma unroll
    for (int dt = 0; dt < 8; ++dt)
#pragma unroll
      for (int r = 0; r < 4; ++r) Oacc[dt][r] *= alpha;
  };

  f32x4 ka[8], va[8];
  auto load_tile = [&](int k0) {
    const float* kp = K + base + (size_t)(k0 + krow) * DH + kcolf;
#pragma unroll
    for (int q = 0; q < 8; ++q) ka[q] = *(const f32x4*)(kp + q * 4);
#pragma unroll
    for (int kk = 0; kk < 2; ++kk) {
      const float* vp = V + base + (size_t)(k0 + vkb + kk * 32) * DH + vd;
#pragma unroll
      for (int i = 0; i < 4; ++i) va[kk*4+i] = *(const f32x4*)(vp + i * DH);
    }
  };
  auto write_tile = [&](int buf) {
    short* ksw = Ks[buf];
    short* vtw = Vt[buf];
#pragma unroll
    for (int q2 = 0; q2 < 4; ++q2) {
      f32x4 a = ka[2*q2], b = ka[2*q2+1];
      union { h16x8 v; unsigned u[4]; } t;
      t.u[0] = pk2(a[0], a[1]); t.u[1] = pk2(a[2], a[3]);
      t.u[2] = pk2(b[0], b[1]); t.u[3] = pk2(b[2], b[3]);
      *(h16x8*)&ksw[krow * KPAD + kcolf + q2 * 8] = t.v;
    }
#pragma unroll
    for (int kk = 0; kk < 2; ++kk) {
      const int c = (vkb + kk * 32) >> 2;
#pragma unroll
      for (int j = 0; j < 4; ++j) {
        const int row = vd + j;
        const int mm = (row ^ (row >> 4)) & 14;
        union { h16x4 v; unsigned u[2]; } t;
        t.u[0] = pk2(va[kk*4+0][j], va[kk*4+1][j]);
        t.u[1] = pk2(va[kk*4+2][j], va[kk*4+3][j]);
        *(h16x4*)&vtw[row * VPAD + ((c ^ mm) << 2)] = t.v;
      }
    }
  };

  // prologue: tile 0 -> buf 0
  load_tile(0);
  write_tile(0);
  __syncthreads();

#pragma unroll 1
  for (int kt = 0; kt < nkt; ++kt) {
    const int k0 = kt * 64;
    const int buf = kt & 1;
    const bool more = (kt + 1 < nkt);

    if (more) load_tile(k0 + 64);   // in flight across QK^T

    const bool actA = (kt <= jq);
    const bool diagA = (kt == jq);
    const bool diagB = (kt == nkt - 1);
    const short* ksb = Ks[buf];
    const short* vtb = Vt[buf];

    // ---- S^T = K * Qs^T (K-fragments shared between strips) ----
    f32x4 stA[4], stB[4];
#pragma unroll
    for (int t = 0; t < 4; ++t) { stA[t] = (f32x4){0.f,0.f,0.f,0.f}; stB[t] = (f32x4){0.f,0.f,0.f,0.f}; }
#pragma unroll
    for (int t = 0; t < 4; ++t) {
      const bool needB = !diagB || (t <= w);          // skip fully-masked diag tiles
      const bool needA = actA && (!diagA || (t <= w));
      if (needB || needA) {
#pragma unroll
        for (int f = 0; f < 4; ++f) {
          h16x8 kf = *(const h16x8*)&ksb[(t * 16 + l16) * KPAD + f * 32 + quad * 8];
          if (needB) stB[t] = __builtin_amdgcn_mfma_f32_16x16x32_f16(kf, qfB[f], stB[t], 0, 0, 0);
          if (needA) stA[t] = __builtin_amdgcn_mfma_f32_16x16x32_f16(kf, qfA[f], stA[t], 0, 0, 0);
        }
      }
    }

    // ---- stage next tile NOW: ka/va (64 regs) die before softmax/PV ----
    if (more) write_tile(buf ^ 1);

    // ---- causal masks (diagonal tiles only) ----
    if (diagB) {
#pragma unroll
      for (int t = 0; t < 4; ++t)
#pragma unroll
        for (int r = 0; r < 4; ++r)
          if (k0 + t * 16 + quad * 4 + r > qrowB) stB[t][r] = -1e30f;
    }
    int pdA[8], pdB[8];
    softmax_pack(stB, mB, lB, OB, pdB);
    if (actA) {
      if (diagA) {
#pragma unroll
        for (int t = 0; t < 4; ++t)
#pragma unroll
          for (int r = 0; r < 4; ++r)
            if (k0 + t * 16 + quad * 4 + r > qrowA) stA[t][r] = -1e30f;
      }
      softmax_pack(stA, mA, lA, OA, pdA);
    }

    // ---- O^T += V^T * P^T (zero-shuffle: pd IS the B-operand) ----
#pragma unroll
    for (int t = 0; t < 4; ++t) {
      union { h16x4 v; int u[2]; } pbB, pbA;
      pbB.u[0] = pdB[2*t]; pbB.u[1] = pdB[2*t+1];
      if (actA) { pbA.u[0] = pdA[2*t]; pbA.u[1] = pdA[2*t+1]; }
#pragma unroll
      for (int dt = 0; dt < 8; ++dt) {
        h16x4 vf = *(const h16x4*)&vtb[vq[dt] + (vt16[dt] ^ (t << 4))];
        OB[dt] = __builtin_amdgcn_mfma_f32_16x16x16f16(vf, pbB.v, OB[dt], 0, 0, 0);
        if (actA) OA[dt] = __builtin_amdgcn_mfma_f32_16x16x16f16(vf, pbA.v, OA[dt], 0, 0, 0);
      }
    }

    __syncthreads();                // single barrier per iteration
  }

  // ---- epilogue: per-lane normalize, direct contiguous f32x4 stores ----
  {
    const float rB = 1.0f / lB;
    const float rA = 1.0f / lA;
    float* opB = O + base + (size_t)qrowB * DH + quad * 4;
    float* opA = O + base + (size_t)qrowA * DH + quad * 4;
#pragma unroll
    for (int dt = 0; dt < 8; ++dt) {
      f32x4 ob, oa;
#pragma unroll
      for (int r = 0; r < 4; ++r) { ob[r] = OB[dt][r] * rB; oa[r] = OA[dt][r] * rA; }
      *(f32x4*)(opB + dt * 16) = ob;
      *(f32x4*)(opA + dt * 16) = oa;
    }
  }
}

extern "C" void kernel_launch(void* const* d_in, const int* in_sizes, int n_in,
                              void* d_out, int out_size, void* d_ws, size_t ws_size,
                              hipStream_t stream) {
  const float* Q  = (const float*)d_in[0];
  const float* K  = (const float*)d_in[1];
  const float* V  = (const float*)d_in[2];
  const float* sc = (const float*)d_in[3];
  float* O = (float*)d_out;
  attn_fwd<<<dim3(512), dim3(256), 0, stream>>>(Q, K, V, sc, O);
}

// Round 4
// 1933.384 us; speedup vs baseline: 1.0087x; 1.0087x over previous
//
#include <hip/hip_runtime.h>
#include <hip/hip_bf16.h>

#define S_LEN 2048
#define DH    128
#define NBH   32
#define KPAD  136         // Ks row pitch in halves (272B)
#define VPAD  72          // Vt row pitch in halves (144B)

typedef __attribute__((ext_vector_type(4))) float    f32x4;
typedef __attribute__((ext_vector_type(8))) _Float16 h16x8;
typedef __attribute__((ext_vector_type(4))) _Float16 h16x4;
typedef __attribute__((ext_vector_type(2))) __fp16   fp16x2;
typedef __attribute__((ext_vector_type(4))) __fp16   fp16x4;

#if __has_builtin(__builtin_amdgcn_exp2f)
#define EXP2(x) __builtin_amdgcn_exp2f(x)
#else
#define EXP2(x) exp2f(x)
#endif

static __device__ __forceinline__ unsigned pk2(float lo, float hi) {
  union { fp16x2 h; unsigned u; } u;
  u.h = __builtin_amdgcn_cvt_pkrtz(lo, hi);
  return u.u;
}

// Block = two 64-row q-strips (jq and 31-jq) of one (b,h), ONE k-sweep.
// XCD swizzle: flat%8 == bh%8 -> all 16 blocks of a (b,h) on one XCD (K/V L2-resident).
// Complementary pairing: CU slots m and m+32 get jq and 15-jq -> 49 iters per CU.
// Double-buffered LDS: ONE barrier per k-iteration.  Staging/QK^T structure is
// round-0-identical (proven no-spill at 128 VGPR).
//
// PV path: O^T += V^T * P^T via v_mfma_f32_16x16x16f16.  The swapped-QK^T
// softmax layout (lane(quad,l16) holds P[q=l16][k=16t+4*quad+r]) IS the
// B-operand layout of the K=16 MFMA -> zero-shuffle PV.  P is packed to the
// B-operand ENTIRELY IN SSA (cvt_pkrtz -> shufflevector -> bit_cast): no int
// arrays, no unions -> nothing for the allocator to demote to scratch
// (rounds 1-3 spilled ~1.7KB/thread/iter through the union-pun path).
// O^T accumulator => alpha and 1/l are per-lane scalars, and lane's O slice
// O[q=l16][d=dt*16+quad*4 .. +3] is a contiguous f32x4 -> direct stores.
__global__ __launch_bounds__(256, 2)
void attn_fwd(const float* __restrict__ Q, const float* __restrict__ K,
              const float* __restrict__ V, const float* __restrict__ scale,
              float* __restrict__ O) {
  __shared__ __align__(16) short Ks[2][64 * KPAD];
  __shared__ __align__(16) short Vt[2][128 * VPAD];

  const int tid  = threadIdx.x;
  const int w    = tid >> 6;
  const int lane = tid & 63;
  const int quad = lane >> 4;
  const int l16  = lane & 15;

  const int flat = (int)blockIdx.x;
  const int m_   = flat >> 3;
  const int jqi  = m_ & 15;
  const int bhh  = m_ >> 4;                       // 0..3
  const int jq   = (bhh & 2) ? (15 - jqi) : jqi;  // complement on second CU slot
  const int bh   = (flat & 7) | (bhh << 3);

  const size_t base = (size_t)bh * (S_LEN * DH);
  const float sc = scale[0] * 1.44269504088896340736f;  // fold log2(e)

  const int krow = tid >> 2, kcolf = (tid & 3) * 32;    // K staging: 4 thr/row
  const int vd = (tid & 31) * 4, vkb = (tid >> 5) * 4;  // V staging: 4k x 4d transpose

  // PV A-operand (V^T) address tables (like round-0's vrow/voff, 16 regs):
  // lane(quad,l16) needs V[k=16t+4*quad+e][d=dt*16+l16], e=0..3
  // = Vt row d, chunk (4t+quad)^mm, mm=(d^(d>>4))&14 (staging swizzle).
  // (4t+quad)^mm = 4*(t^(mm>>2)) + (quad^(mm&2))   (aligned bit fields)
  int vq[8], vt16[8];
#pragma unroll
  for (int dt = 0; dt < 8; ++dt) {
    const int row = dt * 16 + l16;
    const int mm = (row ^ (row >> 4)) & 14;
    vq[dt]   = row * VPAD + ((quad ^ (mm & 2)) << 2);
    vt16[dt] = (mm >> 2) << 4;
  }

  const int q0A = jq * 64;
  const int q0B = (31 - jq) * 64;
  const int nkt = 32 - jq;
  const int qrowA = q0A + w * 16 + l16;
  const int qrowB = q0B + w * 16 + l16;

  h16x8 qfA[4], qfB[4];
  {
    const float* qpA = Q + base + (size_t)qrowA * DH + quad * 8;
    const float* qpB = Q + base + (size_t)qrowB * DH + quad * 8;
#pragma unroll
    for (int f = 0; f < 4; ++f) {
      f32x4 a = *(const f32x4*)(qpA + f * 32);
      f32x4 b = *(const f32x4*)(qpA + f * 32 + 4);
      union { h16x8 v; unsigned u[4]; } t;
      t.u[0] = pk2(a[0] * sc, a[1] * sc);
      t.u[1] = pk2(a[2] * sc, a[3] * sc);
      t.u[2] = pk2(b[0] * sc, b[1] * sc);
      t.u[3] = pk2(b[2] * sc, b[3] * sc);
      qfA[f] = t.v;
      a = *(const f32x4*)(qpB + f * 32);
      b = *(const f32x4*)(qpB + f * 32 + 4);
      t.u[0] = pk2(a[0] * sc, a[1] * sc);
      t.u[1] = pk2(a[2] * sc, a[3] * sc);
      t.u[2] = pk2(b[0] * sc, b[1] * sc);
      t.u[3] = pk2(b[2] * sc, b[3] * sc);
      qfB[f] = t.v;
    }
  }

  // O^T accumulators: O*[dt][r] = O[q=l16][d=dt*16+4*quad+r]
  f32x4 OA[8], OB[8];
#pragma unroll
  for (int i = 0; i < 8; ++i) { OA[i] = (f32x4){0.f,0.f,0.f,0.f}; OB[i] = (f32x4){0.f,0.f,0.f,0.f}; }
  float mA = -1e30f, lA = 0.f, mB = -1e30f, lB = 0.f;

  // Online softmax; per-lane alpha (acc q == l16); emits PV B-operands pv[4]
  // as pure SSA values (no int arrays / unions).
  auto softmax_pack = [&](f32x4* st, float& m_run, float& l_run, f32x4* Oacc, h16x4* pv) {
    float mt = st[0][0];
#pragma unroll
    for (int t = 0; t < 4; ++t)
#pragma unroll
      for (int r = 0; r < 4; ++r) mt = fmaxf(mt, st[t][r]);
    mt = fmaxf(mt, __shfl_xor(mt, 16));
    mt = fmaxf(mt, __shfl_xor(mt, 32));
    const float m_new = fmaxf(m_run, mt);
    const float alpha = EXP2(m_run - m_new);
    m_run = m_new;
    float rs = 0.f;
#pragma unroll
    for (int t = 0; t < 4; ++t) {
      const float p0 = EXP2(st[t][0] - m_new);
      const float p1 = EXP2(st[t][1] - m_new);
      const float p2 = EXP2(st[t][2] - m_new);
      const float p3 = EXP2(st[t][3] - m_new);
      rs += (p0 + p1) + (p2 + p3);
      fp16x2 e01 = __builtin_amdgcn_cvt_pkrtz(p0, p1);
      fp16x2 e23 = __builtin_amdgcn_cvt_pkrtz(p2, p3);
      fp16x4 pf  = __builtin_shufflevector(e01, e23, 0, 1, 2, 3);
      pv[t] = __builtin_bit_cast(h16x4, pf);
    }
    rs += __shfl_xor(rs, 16);
    rs += __shfl_xor(rs, 32);
    l_run = l_run * alpha + rs;
#pragma unroll
    for (int dt = 0; dt < 8; ++dt)
#pragma unroll
      for (int r = 0; r < 4; ++r) Oacc[dt][r] *= alpha;
  };

  f32x4 ka[8], va[8];
  auto load_tile = [&](int k0) {
    const float* kp = K + base + (size_t)(k0 + krow) * DH + kcolf;
#pragma unroll
    for (int q = 0; q < 8; ++q) ka[q] = *(const f32x4*)(kp + q * 4);
#pragma unroll
    for (int kk = 0; kk < 2; ++kk) {
      const float* vp = V + base + (size_t)(k0 + vkb + kk * 32) * DH + vd;
#pragma unroll
      for (int i = 0; i < 4; ++i) va[kk*4+i] = *(const f32x4*)(vp + i * DH);
    }
  };
  auto write_tile = [&](int buf) {
    short* ksw = Ks[buf];
    short* vtw = Vt[buf];
#pragma unroll
    for (int q2 = 0; q2 < 4; ++q2) {
      f32x4 a = ka[2*q2], b = ka[2*q2+1];
      union { h16x8 v; unsigned u[4]; } t;
      t.u[0] = pk2(a[0], a[1]); t.u[1] = pk2(a[2], a[3]);
      t.u[2] = pk2(b[0], b[1]); t.u[3] = pk2(b[2], b[3]);
      *(h16x8*)&ksw[krow * KPAD + kcolf + q2 * 8] = t.v;
    }
#pragma unroll
    for (int kk = 0; kk < 2; ++kk) {
      const int c = (vkb + kk * 32) >> 2;
#pragma unroll
      for (int j = 0; j < 4; ++j) {
        const int row = vd + j;
        const int mm = (row ^ (row >> 4)) & 14;
        union { h16x4 v; unsigned u[2]; } t;
        t.u[0] = pk2(va[kk*4+0][j], va[kk*4+1][j]);
        t.u[1] = pk2(va[kk*4+2][j], va[kk*4+3][j]);
        *(h16x4*)&vtw[row * VPAD + ((c ^ mm) << 2)] = t.v;
      }
    }
  };

  // prologue: tile 0 -> buf 0
  load_tile(0);
  write_tile(0);
  __syncthreads();

#pragma unroll 1
  for (int kt = 0; kt < nkt; ++kt) {
    const int k0 = kt * 64;
    const int buf = kt & 1;
    const bool more = (kt + 1 < nkt);

    if (more) load_tile(k0 + 64);   // in flight across compute

    const bool actA = (kt <= jq);
    const bool diagA = (kt == jq);
    const bool diagB = (kt == nkt - 1);
    const short* ksb = Ks[buf];
    const short* vtb = Vt[buf];

    // ---- S^T = K * Qs^T (K-fragments shared between strips) ----
    f32x4 stA[4], stB[4];
#pragma unroll
    for (int t = 0; t < 4; ++t) { stA[t] = (f32x4){0.f,0.f,0.f,0.f}; stB[t] = (f32x4){0.f,0.f,0.f,0.f}; }
#pragma unroll
    for (int t = 0; t < 4; ++t) {
      const bool needB = !diagB || (t <= w);          // skip fully-masked diag tiles
      const bool needA = actA && (!diagA || (t <= w));
      if (needB || needA) {
#pragma unroll
        for (int f = 0; f < 4; ++f) {
          h16x8 kf = *(const h16x8*)&ksb[(t * 16 + l16) * KPAD + f * 32 + quad * 8];
          if (needB) stB[t] = __builtin_amdgcn_mfma_f32_16x16x32_f16(kf, qfB[f], stB[t], 0, 0, 0);
          if (needA) stA[t] = __builtin_amdgcn_mfma_f32_16x16x32_f16(kf, qfA[f], stA[t], 0, 0, 0);
        }
      }
    }

    // ---- causal masks (diagonal tiles only) ----
    if (diagB) {
#pragma unroll
      for (int t = 0; t < 4; ++t)
#pragma unroll
        for (int r = 0; r < 4; ++r)
          if (k0 + t * 16 + quad * 4 + r > qrowB) stB[t][r] = -1e30f;
    }
    h16x4 pvA[4], pvB[4];
    softmax_pack(stB, mB, lB, OB, pvB);
    if (actA) {
      if (diagA) {
#pragma unroll
        for (int t = 0; t < 4; ++t)
#pragma unroll
          for (int r = 0; r < 4; ++r)
            if (k0 + t * 16 + quad * 4 + r > qrowA) stA[t][r] = -1e30f;
      }
      softmax_pack(stA, mA, lA, OA, pvA);
    }

    // ---- O^T += V^T * P^T (zero-shuffle: pv IS the B-operand) ----
#pragma unroll
    for (int t = 0; t < 4; ++t) {
#pragma unroll
      for (int dt = 0; dt < 8; ++dt) {
        h16x4 vf = *(const h16x4*)&vtb[vq[dt] + (vt16[dt] ^ (t << 4))];
        OB[dt] = __builtin_amdgcn_mfma_f32_16x16x16f16(vf, pvB[t], OB[dt], 0, 0, 0);
        if (actA) OA[dt] = __builtin_amdgcn_mfma_f32_16x16x16f16(vf, pvA[t], OA[dt], 0, 0, 0);
      }
    }

    if (more) write_tile(buf ^ 1);  // next tile into other buffer (round-0 position)
    __syncthreads();                // single barrier per iteration
  }

  // ---- epilogue: per-lane normalize, direct contiguous f32x4 stores ----
  {
    const float rB = 1.0f / lB;
    const float rA = 1.0f / lA;
    float* opB = O + base + (size_t)qrowB * DH + quad * 4;
    float* opA = O + base + (size_t)qrowA * DH + quad * 4;
#pragma unroll
    for (int dt = 0; dt < 8; ++dt) {
      f32x4 ob, oa;
#pragma unroll
      for (int r = 0; r < 4; ++r) { ob[r] = OB[dt][r] * rB; oa[r] = OA[dt][r] * rA; }
      *(f32x4*)(opB + dt * 16) = ob;
      *(f32x4*)(opA + dt * 16) = oa;
    }
  }
}

extern "C" void kernel_launch(void* const* d_in, const int* in_sizes, int n_in,
                              void* d_out, int out_size, void* d_ws, size_t ws_size,
                              hipStream_t stream) {
  const float* Q  = (const float*)d_in[0];
  const float* K  = (const float*)d_in[1];
  const float* V  = (const float*)d_in[2];
  const float* sc = (const float*)d_in[3];
  float* O = (float*)d_out;
  attn_fwd<<<dim3(512), dim3(256), 0, stream>>>(Q, K, V, sc, O);
}

// Round 6
// 300.017 us; speedup vs baseline: 6.5004x; 6.4442x over previous
//
#include <hip/hip_runtime.h>
#include <hip/hip_bf16.h>

#define S_LEN 2048
#define DH    128
#define NBH   32
#define KPAD  138         // Ks row pitch in halves (276B = 69 dw; 69 mod 32 = 5 -> 2-way max on K read/write)
#define VPAD  72          // Vt row pitch in halves (144B)

typedef __attribute__((ext_vector_type(4))) float    f32x4;
typedef __attribute__((ext_vector_type(8))) _Float16 h16x8;
typedef __attribute__((ext_vector_type(4))) _Float16 h16x4;
typedef __attribute__((ext_vector_type(2))) __fp16   fp16x2;

#if __has_builtin(__builtin_amdgcn_exp2f)
#define EXP2(x) __builtin_amdgcn_exp2f(x)
#else
#define EXP2(x) exp2f(x)
#endif

static __device__ __forceinline__ unsigned pk2(float lo, float hi) {
  union { fp16x2 h; unsigned u; } u;
  u.h = __builtin_amdgcn_cvt_pkrtz(lo, hi);
  return u.u;
}

// Round-0 structure (proven 242us, spill-free at 128 VGPR), plus:
//  - KPAD 136->138: K LDS read was 8-way bank-conflicted (68dw row pitch ==
//    4 mod 32 -> bank 4*(l16+quad), 8 banks for 64 lanes); 69dw pitch is odd
//    multiplier mod 32 -> worst 2-way (free).  Same fix applies to K staging
//    writes.  SQ_LDS_BANK_CONFLICT was 12% of round-0 cycles.
//  - T5 s_setprio(1) around QK^T and PV MFMA clusters: 2 independent
//    blocks/CU at different k-phases -> scheduler favors MFMA-issuing waves
//    (m191: +4-7% on attn with independent waves).
__global__ __launch_bounds__(256, 2)
void attn_fwd(const float* __restrict__ Q, const float* __restrict__ K,
              const float* __restrict__ V, const float* __restrict__ scale,
              float* __restrict__ O) {
  __shared__ short Ks[2][64 * KPAD];
  __shared__ short Vt[2][128 * VPAD];

  const int tid  = threadIdx.x;
  const int w    = tid >> 6;
  const int lane = tid & 63;
  const int quad = lane >> 4;
  const int l16  = lane & 15;

  const int flat = (int)blockIdx.x;
  const int m_   = flat >> 3;
  const int jqi  = m_ & 15;
  const int bhh  = m_ >> 4;                       // 0..3
  const int jq   = (bhh & 2) ? (15 - jqi) : jqi;  // complement on second CU slot
  const int bh   = (flat & 7) | (bhh << 3);

  const size_t base = (size_t)bh * (S_LEN * DH);
  const float sc = scale[0] * 1.44269504088896340736f;  // fold log2(e)

  const int krow = tid >> 2, kcolf = (tid & 3) * 32;    // K staging: 4 thr/row
  const int vd = (tid & 31) * 4, vkb = (tid >> 5) * 4;  // V staging: 4k x 4d transpose

  int vrow[8], voff[8];
#pragma unroll
  for (int dt = 0; dt < 8; ++dt) {
    const int row = dt * 16 + l16;
    const int mm = (row ^ (row >> 4)) & 14;
    vrow[dt] = row * VPAD;
    voff[dt] = ((quad * 2) ^ mm) << 2;
  }

  const int q0A = jq * 64;
  const int q0B = (31 - jq) * 64;
  const int nkt = 32 - jq;
  const int qrowA = q0A + w * 16 + l16;
  const int qrowB = q0B + w * 16 + l16;

  h16x8 qfA[4], qfB[4];
  {
    const float* qpA = Q + base + (size_t)qrowA * DH + quad * 8;
    const float* qpB = Q + base + (size_t)qrowB * DH + quad * 8;
#pragma unroll
    for (int f = 0; f < 4; ++f) {
      f32x4 a = *(const f32x4*)(qpA + f * 32);
      f32x4 b = *(const f32x4*)(qpA + f * 32 + 4);
      union { h16x8 v; unsigned u[4]; } t;
      t.u[0] = pk2(a[0] * sc, a[1] * sc);
      t.u[1] = pk2(a[2] * sc, a[3] * sc);
      t.u[2] = pk2(b[0] * sc, b[1] * sc);
      t.u[3] = pk2(b[2] * sc, b[3] * sc);
      qfA[f] = t.v;
      a = *(const f32x4*)(qpB + f * 32);
      b = *(const f32x4*)(qpB + f * 32 + 4);
      t.u[0] = pk2(a[0] * sc, a[1] * sc);
      t.u[1] = pk2(a[2] * sc, a[3] * sc);
      t.u[2] = pk2(b[0] * sc, b[1] * sc);
      t.u[3] = pk2(b[2] * sc, b[3] * sc);
      qfB[f] = t.v;
    }
  }

  f32x4 OA[8], OB[8];
#pragma unroll
  for (int i = 0; i < 8; ++i) { OA[i] = (f32x4){0.f,0.f,0.f,0.f}; OB[i] = (f32x4){0.f,0.f,0.f,0.f}; }
  float mA = -1e30f, lA = 0.f, mB = -1e30f, lB = 0.f;

  auto softmax_pack = [&](f32x4* st, float& m_run, float& l_run, f32x4* Oacc, int* pd) {
    float mt = st[0][0];
#pragma unroll
    for (int t = 0; t < 4; ++t)
#pragma unroll
      for (int r = 0; r < 4; ++r) mt = fmaxf(mt, st[t][r]);
    mt = fmaxf(mt, __shfl_xor(mt, 16));
    mt = fmaxf(mt, __shfl_xor(mt, 32));
    const float m_new = fmaxf(m_run, mt);
    float p[16], rs = 0.f;
#pragma unroll
    for (int t = 0; t < 4; ++t)
#pragma unroll
      for (int r = 0; r < 4; ++r) { p[t*4+r] = EXP2(st[t][r] - m_new); rs += p[t*4+r]; }
    rs += __shfl_xor(rs, 16);
    rs += __shfl_xor(rs, 32);
    const float alpha = EXP2(m_run - m_new);
    l_run = l_run * alpha + rs;
    m_run = m_new;
    float aO[4];
#pragma unroll
    for (int r = 0; r < 4; ++r) aO[r] = __shfl(alpha, quad * 4 + r);
#pragma unroll
    for (int dt = 0; dt < 8; ++dt)
#pragma unroll
      for (int r = 0; r < 4; ++r) Oacc[dt][r] *= aO[r];
#pragma unroll
    for (int t = 0; t < 4; ++t) {
      pd[t*2]   = (int)pk2(p[t*4+0], p[t*4+1]);
      pd[t*2+1] = (int)pk2(p[t*4+2], p[t*4+3]);
    }
  };

  f32x4 ka[8], va[8];
  auto load_tile = [&](int k0) {
    const float* kp = K + base + (size_t)(k0 + krow) * DH + kcolf;
#pragma unroll
    for (int q = 0; q < 8; ++q) ka[q] = *(const f32x4*)(kp + q * 4);
#pragma unroll
    for (int kk = 0; kk < 2; ++kk) {
      const float* vp = V + base + (size_t)(k0 + vkb + kk * 32) * DH + vd;
#pragma unroll
      for (int i = 0; i < 4; ++i) va[kk*4+i] = *(const f32x4*)(vp + i * DH);
    }
  };
  auto write_tile = [&](int buf) {
    short* ksw = Ks[buf];
    short* vtw = Vt[buf];
#pragma unroll
    for (int q2 = 0; q2 < 4; ++q2) {
      f32x4 a = ka[2*q2], b = ka[2*q2+1];
      union { h16x8 v; unsigned u[4]; } t;
      t.u[0] = pk2(a[0], a[1]); t.u[1] = pk2(a[2], a[3]);
      t.u[2] = pk2(b[0], b[1]); t.u[3] = pk2(b[2], b[3]);
      *(h16x8*)&ksw[krow * KPAD + kcolf + q2 * 8] = t.v;
    }
#pragma unroll
    for (int kk = 0; kk < 2; ++kk) {
      const int c = (vkb + kk * 32) >> 2;
#pragma unroll
      for (int j = 0; j < 4; ++j) {
        const int row = vd + j;
        const int mm = (row ^ (row >> 4)) & 14;
        union { h16x4 v; unsigned u[2]; } t;
        t.u[0] = pk2(va[kk*4+0][j], va[kk*4+1][j]);
        t.u[1] = pk2(va[kk*4+2][j], va[kk*4+3][j]);
        *(h16x4*)&vtw[row * VPAD + ((c ^ mm) << 2)] = t.v;
      }
    }
  };

  // prologue: tile 0 -> buf 0
  load_tile(0);
  write_tile(0);
  __syncthreads();

#pragma unroll 1
  for (int kt = 0; kt < nkt; ++kt) {
    const int k0 = kt * 64;
    const int buf = kt & 1;
    const bool more = (kt + 1 < nkt);

    if (more) load_tile(k0 + 64);   // in flight across compute

    const bool actA = (kt <= jq);
    const bool diagA = (kt == jq);
    const bool diagB = (kt == nkt - 1);
    const short* ksb = Ks[buf];
    const short* vtb = Vt[buf];

    // ---- S^T = K * Qs^T (K-fragments shared between strips) ----
    f32x4 stA[4], stB[4];
#pragma unroll
    for (int t = 0; t < 4; ++t) { stA[t] = (f32x4){0.f,0.f,0.f,0.f}; stB[t] = (f32x4){0.f,0.f,0.f,0.f}; }
    __builtin_amdgcn_s_setprio(1);
#pragma unroll
    for (int t = 0; t < 4; ++t) {
      const bool needB = !diagB || (t <= w);          // skip fully-masked diag tiles
      const bool needA = actA && (!diagA || (t <= w));
      if (needB || needA) {
#pragma unroll
        for (int f = 0; f < 4; ++f) {
          h16x8 kf = *(const h16x8*)&ksb[(t * 16 + l16) * KPAD + f * 32 + quad * 8];
          if (needB) stB[t] = __builtin_amdgcn_mfma_f32_16x16x32_f16(kf, qfB[f], stB[t], 0, 0, 0);
          if (needA) stA[t] = __builtin_amdgcn_mfma_f32_16x16x32_f16(kf, qfA[f], stA[t], 0, 0, 0);
        }
      }
    }
    __builtin_amdgcn_s_setprio(0);

    // ---- causal masks (diagonal tiles only) ----
    if (diagB) {
#pragma unroll
      for (int t = 0; t < 4; ++t)
#pragma unroll
        for (int r = 0; r < 4; ++r)
          if (k0 + t * 16 + quad * 4 + r > qrowB) stB[t][r] = -1e30f;
    }
    int pdA[8], pdB[8];
    softmax_pack(stB, mB, lB, OB, pdB);
    if (actA) {
      if (diagA) {
#pragma unroll
        for (int t = 0; t < 4; ++t)
#pragma unroll
          for (int r = 0; r < 4; ++r)
            if (k0 + t * 16 + quad * 4 + r > qrowA) stA[t][r] = -1e30f;
      }
      softmax_pack(stA, mA, lA, OA, pdA);
    }

    // ---- P transform (C->A layout) + O += P*V (V-fragments shared) ----
#pragma unroll
    for (int h = 0; h < 2; ++h) {
      union { h16x8 v; int u[4]; } paA, paB;
#pragma unroll
      for (int hp = 0; hp < 4; ++hp) {
        const int src = (2 * (quad & 1) + (hp >> 1)) * 16 + l16;
        int va_ = __shfl(pdB[4*h + (hp & 1)], src);
        int vb_ = __shfl(pdB[4*h + 2 + (hp & 1)], src);
        paB.u[hp] = (quad >= 2) ? vb_ : va_;
        if (actA) {
          va_ = __shfl(pdA[4*h + (hp & 1)], src);
          vb_ = __shfl(pdA[4*h + 2 + (hp & 1)], src);
          paA.u[hp] = (quad >= 2) ? vb_ : va_;
        }
      }
      __builtin_amdgcn_s_setprio(1);
#pragma unroll
      for (int dt = 0; dt < 8; ++dt) {
        const int off0 = vrow[dt] + (voff[dt] ^ (h << 5));
        h16x8 vf = *(const h16x8*)&vtb[off0];
        OB[dt] = __builtin_amdgcn_mfma_f32_16x16x32_f16(paB.v, vf, OB[dt], 0, 0, 0);
        if (actA) OA[dt] = __builtin_amdgcn_mfma_f32_16x16x32_f16(paA.v, vf, OA[dt], 0, 0, 0);
      }
      __builtin_amdgcn_s_setprio(0);
    }

    if (more) write_tile(buf ^ 1);  // next tile into other buffer
    __syncthreads();                // single barrier per iteration
  }

  // ---- epilogue ----
  auto store_o = [&](f32x4* Oacc, float l_run, int q0) {
    float lO[4];
#pragma unroll
    for (int r = 0; r < 4; ++r) lO[r] = 1.0f / __shfl(l_run, quad * 4 + r);
#pragma unroll
    for (int dt = 0; dt < 8; ++dt)
#pragma unroll
      for (int r = 0; r < 4; ++r) {
        const size_t row = q0 + w * 16 + quad * 4 + r;
        O[base + row * DH + dt * 16 + l16] = Oacc[dt][r] * lO[r];
      }
  };
  store_o(OB, lB, q0B);
  store_o(OA, lA, q0A);
}

extern "C" void kernel_launch(void* const* d_in, const int* in_sizes, int n_in,
                              void* d_out, int out_size, void* d_ws, size_t ws_size,
                              hipStream_t stream) {
  const float* Q  = (const float*)d_in[0];
  const float* K  = (const float*)d_in[1];
  const float* V  = (const float*)d_in[2];
  const float* sc = (const float*)d_in[3];
  float* O = (float*)d_out;
  attn_fwd<<<dim3(512), dim3(256), 0, stream>>>(Q, K, V, sc, O);
}

// Round 8
// 242.818 us; speedup vs baseline: 8.0317x; 1.2356x over previous
//
#include <hip/hip_runtime.h>
#include <hip/hip_bf16.h>

#define S_LEN 2048
#define DH    128
#define NBH   32
#define KPAD  136         // Ks row pitch in halves (272B, multiple of 16B -> b128 ops stay b128)
#define VPAD  72          // Vt row pitch in halves (144B)

typedef __attribute__((ext_vector_type(4))) float    f32x4;
typedef __attribute__((ext_vector_type(8))) _Float16 h16x8;
typedef __attribute__((ext_vector_type(4))) _Float16 h16x4;
typedef __attribute__((ext_vector_type(2))) __fp16   fp16x2;

#if __has_builtin(__builtin_amdgcn_exp2f)
#define EXP2(x) __builtin_amdgcn_exp2f(x)
#else
#define EXP2(x) exp2f(x)
#endif

static __device__ __forceinline__ unsigned pk2(float lo, float hi) {
  union { fp16x2 h; unsigned u; } u;
  u.h = __builtin_amdgcn_cvt_pkrtz(lo, hi);
  return u.u;
}

// ROUND-0 VERBATIM (verified 242.7us, spill-free, 128 VGPR) + T5 setprio ONLY.
// Block = two 64-row q-strips (jq and 31-jq) of one (b,h), ONE k-sweep.
// XCD swizzle: flat%8 == bh%8 -> all 16 blocks of a (b,h) on one XCD (K/V L2-resident).
// Complementary pairing: CU slots m and m+32 get jq and 15-jq -> 49 iters per CU.
// Double-buffered LDS: ONE barrier per k-iteration.
// T5: s_setprio(1) around the two MFMA clusters.  Round-0 is m191's positive
// regime (2 INDEPENDENT blocks/CU at different k-phases, no lockstep) where
// isolated setprio measured +4-7%.  Pure scheduler hint - output bit-identical.
// (Round-6's regression was the KPAD=138 misalignment: 276B pitch not 16B-
// multiple -> all K-path b128 LDS ops split.  KPAD stays 136.)
__global__ __launch_bounds__(256, 2)
void attn_fwd(const float* __restrict__ Q, const float* __restrict__ K,
              const float* __restrict__ V, const float* __restrict__ scale,
              float* __restrict__ O) {
  __shared__ short Ks[2][64 * KPAD];
  __shared__ short Vt[2][128 * VPAD];

  const int tid  = threadIdx.x;
  const int w    = tid >> 6;
  const int lane = tid & 63;
  const int quad = lane >> 4;
  const int l16  = lane & 15;

  const int flat = (int)blockIdx.x;
  const int m_   = flat >> 3;
  const int jqi  = m_ & 15;
  const int bhh  = m_ >> 4;                       // 0..3
  const int jq   = (bhh & 2) ? (15 - jqi) : jqi;  // complement on second CU slot
  const int bh   = (flat & 7) | (bhh << 3);

  const size_t base = (size_t)bh * (S_LEN * DH);
  const float sc = scale[0] * 1.44269504088896340736f;  // fold log2(e)

  const int krow = tid >> 2, kcolf = (tid & 3) * 32;    // K staging: 4 thr/row
  const int vd = (tid & 31) * 4, vkb = (tid >> 5) * 4;  // V staging: 4k x 4d transpose

  int vrow[8], voff[8];
#pragma unroll
  for (int dt = 0; dt < 8; ++dt) {
    const int row = dt * 16 + l16;
    const int mm = (row ^ (row >> 4)) & 14;
    vrow[dt] = row * VPAD;
    voff[dt] = ((quad * 2) ^ mm) << 2;
  }

  const int q0A = jq * 64;
  const int q0B = (31 - jq) * 64;
  const int nkt = 32 - jq;
  const int qrowA = q0A + w * 16 + l16;
  const int qrowB = q0B + w * 16 + l16;

  h16x8 qfA[4], qfB[4];
  {
    const float* qpA = Q + base + (size_t)qrowA * DH + quad * 8;
    const float* qpB = Q + base + (size_t)qrowB * DH + quad * 8;
#pragma unroll
    for (int f = 0; f < 4; ++f) {
      f32x4 a = *(const f32x4*)(qpA + f * 32);
      f32x4 b = *(const f32x4*)(qpA + f * 32 + 4);
      union { h16x8 v; unsigned u[4]; } t;
      t.u[0] = pk2(a[0] * sc, a[1] * sc);
      t.u[1] = pk2(a[2] * sc, a[3] * sc);
      t.u[2] = pk2(b[0] * sc, b[1] * sc);
      t.u[3] = pk2(b[2] * sc, b[3] * sc);
      qfA[f] = t.v;
      a = *(const f32x4*)(qpB + f * 32);
      b = *(const f32x4*)(qpB + f * 32 + 4);
      t.u[0] = pk2(a[0] * sc, a[1] * sc);
      t.u[1] = pk2(a[2] * sc, a[3] * sc);
      t.u[2] = pk2(b[0] * sc, b[1] * sc);
      t.u[3] = pk2(b[2] * sc, b[3] * sc);
      qfB[f] = t.v;
    }
  }

  f32x4 OA[8], OB[8];
#pragma unroll
  for (int i = 0; i < 8; ++i) { OA[i] = (f32x4){0.f,0.f,0.f,0.f}; OB[i] = (f32x4){0.f,0.f,0.f,0.f}; }
  float mA = -1e30f, lA = 0.f, mB = -1e30f, lB = 0.f;

  auto softmax_pack = [&](f32x4* st, float& m_run, float& l_run, f32x4* Oacc, int* pd) {
    float mt = st[0][0];
#pragma unroll
    for (int t = 0; t < 4; ++t)
#pragma unroll
      for (int r = 0; r < 4; ++r) mt = fmaxf(mt, st[t][r]);
    mt = fmaxf(mt, __shfl_xor(mt, 16));
    mt = fmaxf(mt, __shfl_xor(mt, 32));
    const float m_new = fmaxf(m_run, mt);
    float p[16], rs = 0.f;
#pragma unroll
    for (int t = 0; t < 4; ++t)
#pragma unroll
      for (int r = 0; r < 4; ++r) { p[t*4+r] = EXP2(st[t][r] - m_new); rs += p[t*4+r]; }
    rs += __shfl_xor(rs, 16);
    rs += __shfl_xor(rs, 32);
    const float alpha = EXP2(m_run - m_new);
    l_run = l_run * alpha + rs;
    m_run = m_new;
    float aO[4];
#pragma unroll
    for (int r = 0; r < 4; ++r) aO[r] = __shfl(alpha, quad * 4 + r);
#pragma unroll
    for (int dt = 0; dt < 8; ++dt)
#pragma unroll
      for (int r = 0; r < 4; ++r) Oacc[dt][r] *= aO[r];
#pragma unroll
    for (int t = 0; t < 4; ++t) {
      pd[t*2]   = (int)pk2(p[t*4+0], p[t*4+1]);
      pd[t*2+1] = (int)pk2(p[t*4+2], p[t*4+3]);
    }
  };

  f32x4 ka[8], va[8];
  auto load_tile = [&](int k0) {
    const float* kp = K + base + (size_t)(k0 + krow) * DH + kcolf;
#pragma unroll
    for (int q = 0; q < 8; ++q) ka[q] = *(const f32x4*)(kp + q * 4);
#pragma unroll
    for (int kk = 0; kk < 2; ++kk) {
      const float* vp = V + base + (size_t)(k0 + vkb + kk * 32) * DH + vd;
#pragma unroll
      for (int i = 0; i < 4; ++i) va[kk*4+i] = *(const f32x4*)(vp + i * DH);
    }
  };
  auto write_tile = [&](int buf) {
    short* ksw = Ks[buf];
    short* vtw = Vt[buf];
#pragma unroll
    for (int q2 = 0; q2 < 4; ++q2) {
      f32x4 a = ka[2*q2], b = ka[2*q2+1];
      union { h16x8 v; unsigned u[4]; } t;
      t.u[0] = pk2(a[0], a[1]); t.u[1] = pk2(a[2], a[3]);
      t.u[2] = pk2(b[0], b[1]); t.u[3] = pk2(b[2], b[3]);
      *(h16x8*)&ksw[krow * KPAD + kcolf + q2 * 8] = t.v;
    }
#pragma unroll
    for (int kk = 0; kk < 2; ++kk) {
      const int c = (vkb + kk * 32) >> 2;
#pragma unroll
      for (int j = 0; j < 4; ++j) {
        const int row = vd + j;
        const int mm = (row ^ (row >> 4)) & 14;
        union { h16x4 v; unsigned u[2]; } t;
        t.u[0] = pk2(va[kk*4+0][j], va[kk*4+1][j]);
        t.u[1] = pk2(va[kk*4+2][j], va[kk*4+3][j]);
        *(h16x4*)&vtw[row * VPAD + ((c ^ mm) << 2)] = t.v;
      }
    }
  };

  // prologue: tile 0 -> buf 0
  load_tile(0);
  write_tile(0);
  __syncthreads();

#pragma unroll 1
  for (int kt = 0; kt < nkt; ++kt) {
    const int k0 = kt * 64;
    const int buf = kt & 1;
    const bool more = (kt + 1 < nkt);

    if (more) load_tile(k0 + 64);   // in flight across compute

    const bool actA = (kt <= jq);
    const bool diagA = (kt == jq);
    const bool diagB = (kt == nkt - 1);
    const short* ksb = Ks[buf];
    const short* vtb = Vt[buf];

    // ---- S^T = K * Qs^T (K-fragments shared between strips) ----
    f32x4 stA[4], stB[4];
#pragma unroll
    for (int t = 0; t < 4; ++t) { stA[t] = (f32x4){0.f,0.f,0.f,0.f}; stB[t] = (f32x4){0.f,0.f,0.f,0.f}; }
    __builtin_amdgcn_s_setprio(1);
#pragma unroll
    for (int t = 0; t < 4; ++t) {
      const bool needB = !diagB || (t <= w);          // skip fully-masked diag tiles
      const bool needA = actA && (!diagA || (t <= w));
      if (needB || needA) {
#pragma unroll
        for (int f = 0; f < 4; ++f) {
          h16x8 kf = *(const h16x8*)&ksb[(t * 16 + l16) * KPAD + f * 32 + quad * 8];
          if (needB) stB[t] = __builtin_amdgcn_mfma_f32_16x16x32_f16(kf, qfB[f], stB[t], 0, 0, 0);
          if (needA) stA[t] = __builtin_amdgcn_mfma_f32_16x16x32_f16(kf, qfA[f], stA[t], 0, 0, 0);
        }
      }
    }
    __builtin_amdgcn_s_setprio(0);

    // ---- causal masks (diagonal tiles only) ----
    if (diagB) {
#pragma unroll
      for (int t = 0; t < 4; ++t)
#pragma unroll
        for (int r = 0; r < 4; ++r)
          if (k0 + t * 16 + quad * 4 + r > qrowB) stB[t][r] = -1e30f;
    }
    int pdA[8], pdB[8];
    softmax_pack(stB, mB, lB, OB, pdB);
    if (actA) {
      if (diagA) {
#pragma unroll
        for (int t = 0; t < 4; ++t)
#pragma unroll
          for (int r = 0; r < 4; ++r)
            if (k0 + t * 16 + quad * 4 + r > qrowA) stA[t][r] = -1e30f;
      }
      softmax_pack(stA, mA, lA, OA, pdA);
    }

    // ---- P transform (C->A layout) + O += P*V (V-fragments shared) ----
#pragma unroll
    for (int h = 0; h < 2; ++h) {
      union { h16x8 v; int u[4]; } paA, paB;
#pragma unroll
      for (int hp = 0; hp < 4; ++hp) {
        const int src = (2 * (quad & 1) + (hp >> 1)) * 16 + l16;
        int va_ = __shfl(pdB[4*h + (hp & 1)], src);
        int vb_ = __shfl(pdB[4*h + 2 + (hp & 1)], src);
        paB.u[hp] = (quad >= 2) ? vb_ : va_;
        if (actA) {
          va_ = __shfl(pdA[4*h + (hp & 1)], src);
          vb_ = __shfl(pdA[4*h + 2 + (hp & 1)], src);
          paA.u[hp] = (quad >= 2) ? vb_ : va_;
        }
      }
      __builtin_amdgcn_s_setprio(1);
#pragma unroll
      for (int dt = 0; dt < 8; ++dt) {
        const int off0 = vrow[dt] + (voff[dt] ^ (h << 5));
        h16x8 vf = *(const h16x8*)&vtb[off0];
        OB[dt] = __builtin_amdgcn_mfma_f32_16x16x32_f16(paB.v, vf, OB[dt], 0, 0, 0);
        if (actA) OA[dt] = __builtin_amdgcn_mfma_f32_16x16x32_f16(paA.v, vf, OA[dt], 0, 0, 0);
      }
      __builtin_amdgcn_s_setprio(0);
    }

    if (more) write_tile(buf ^ 1);  // next tile into other buffer
    __syncthreads();                // single barrier per iteration
  }

  // ---- epilogue ----
  auto store_o = [&](f32x4* Oacc, float l_run, int q0) {
    float lO[4];
#pragma unroll
    for (int r = 0; r < 4; ++r) lO[r] = 1.0f / __shfl(l_run, quad * 4 + r);
#pragma unroll
    for (int dt = 0; dt < 8; ++dt)
#pragma unroll
      for (int r = 0; r < 4; ++r) {
        const size_t row = q0 + w * 16 + quad * 4 + r;
        O[base + row * DH + dt * 16 + l16] = Oacc[dt][r] * lO[r];
      }
  };
  store_o(OB, lB, q0B);
  store_o(OA, lA, q0A);
}

extern "C" void kernel_launch(void* const* d_in, const int* in_sizes, int n_in,
                              void* d_out, int out_size, void* d_ws, size_t ws_size,
                              hipStream_t stream) {
  const float* Q  = (const float*)d_in[0];
  const float* K  = (const float*)d_in[1];
  const float* V  = (const float*)d_in[2];
  const float* sc = (const float*)d_in[3];
  float* O = (float*)d_out;
  attn_fwd<<<dim3(512), dim3(256), 0, stream>>>(Q, K, V, sc, O);
}